// Round 2
// baseline (171.807 us; speedup 1.0000x reference)
//
#include <hip/hip_runtime.h>
#include <hip/hip_bf16.h>

// IsometricLoss: loss = (1/N) * sum_{i,m} r[i,m] * max(||X_i||^2 + ||mu_m||^2 - 2 X_i.mu_m, 0)
// N=131072, M=128, D=128, fp32 in, fp32 scalar out.
//
// R2: barrier-free structure. No LDS staging — each wave loads its MFMA
// A-fragments directly from global (lane = row). Removes both __syncthreads
// (and their vmcnt(0) drains) from the loop so all loads overlap across
// phases/iterations/waves. x2 exact fp32 via shuffle combine + bpermute gather.

typedef __attribute__((ext_vector_type(8)))  short  short8;   // 8 bf16 (MFMA A/B frag)
typedef __attribute__((ext_vector_type(16))) float  float16v; // MFMA 32x32 accumulator

#if defined(__has_builtin)
#if __has_builtin(__builtin_amdgcn_cvt_pk_bf16_f32)
#define HAVE_PK_BF16 1
#endif
#endif

__device__ __forceinline__ unsigned int pk_bf16(float x, float y) {
#ifdef HAVE_PK_BF16
    typedef __attribute__((ext_vector_type(2))) __bf16 bf16x2;
    bf16x2 p = __builtin_amdgcn_cvt_pk_bf16_f32(x, y);
    return __builtin_bit_cast(unsigned int, p);
#else
    // round-to-nearest-even fp32 -> bf16, packed pair (inputs finite normals)
    unsigned int ux = __float_as_uint(x);
    unsigned int uy = __float_as_uint(y);
    ux += 0x7fffu + ((ux >> 16) & 1u);
    uy += 0x7fffu + ((uy >> 16) & 1u);
    return (ux >> 16) | (uy & 0xffff0000u);
#endif
}

__global__ void zero_out_kernel(float* out) { out[0] = 0.0f; }

__global__ __launch_bounds__(256, 4)
void isoloss_kernel(const float* __restrict__ X,
                    const float* __restrict__ r,
                    const float* __restrict__ mus,
                    float* __restrict__ out)
{
    const int tid  = threadIdx.x;
    const int wave = tid >> 6;    // 0..3 -> which 32-mu tile this wave owns
    const int lane = tid & 63;
    const int col  = lane & 31;   // MFMA n-index (mu) == m-index (row) for A
    const int half = lane >> 5;   // 0/1 -> which k-half this lane covers

    __shared__ float wsum[4];

    // ---- preload B fragments (this wave's 32 mus) into registers + exact fp32 mu2 ----
    // B[k=(lane>>5)*8+j][n=lane&31] = mus[col][ks*16 + half*8 + j]
    short8 bfrag[8];
    float mu2p = 0.0f;
    {
        const float* mrow = mus + (size_t)(wave * 32 + col) * 128 + half * 8;
        #pragma unroll
        for (int ks = 0; ks < 8; ++ks) {
            const float4 a = *(const float4*)(mrow + ks * 16);
            const float4 b = *(const float4*)(mrow + ks * 16 + 4);
            mu2p += a.x*a.x + a.y*a.y + a.z*a.z + a.w*a.w
                  + b.x*b.x + b.y*b.y + b.z*b.z + b.w*b.w;
            union { short8 s8; uint4 u4; } u;
            u.u4.x = pk_bf16(a.x, a.y);
            u.u4.y = pk_bf16(a.z, a.w);
            u.u4.z = pk_bf16(b.x, b.y);
            u.u4.w = pk_bf16(b.z, b.w);
            bfrag[ks] = u.s8;
        }
    }
    // each lane covered half the k-range of its mu; combine halves -> exact mu2[col]
    const float mu2 = mu2p + __shfl_xor(mu2p, 32);

    float s = 0.0f;

    for (int g = blockIdx.x; g < 4096; g += gridDim.x) {
        const int rowbase = g * 32;
        // A[m=col][k=half*8+ks*16+j] = X[rowbase+col][...] -> direct global loads
        const float* xp = X + (size_t)(rowbase + col) * 128 + half * 8;
        const float* rp = r + (size_t)rowbase * 128 + wave * 32 + col;

        // r loads issued first: independent, stay in flight through the MFMA work.
        // C/D row for reg: rl = (reg&3) + 8*(reg>>2) + 4*half (verified mapping).
        float rv[16];
        #pragma unroll
        for (int reg = 0; reg < 16; ++reg) {
            const int rl = (reg & 3) + 8 * (reg >> 2) + 4 * half;
            rv[reg] = rp[(size_t)rl * 128];
        }

        float16v acc = {};
        float p = 0.0f;
        #pragma unroll
        for (int ks = 0; ks < 8; ++ks) {
            const float4 a = *(const float4*)(xp + ks * 16);
            const float4 b = *(const float4*)(xp + ks * 16 + 4);
            p += a.x*a.x + a.y*a.y + a.z*a.z + a.w*a.w
               + b.x*b.x + b.y*b.y + b.z*b.z + b.w*b.w;
            union { short8 s8; uint4 u4; } u;
            u.u4.x = pk_bf16(a.x, a.y);
            u.u4.y = pk_bf16(a.z, a.w);
            u.u4.z = pk_bf16(b.x, b.y);
            u.u4.w = pk_bf16(b.z, b.w);
            acc = __builtin_amdgcn_mfma_f32_32x32x16_bf16(u.s8, bfrag[ks], acc, 0, 0, 0);
        }
        // exact x2 for row (rowbase+col): combine this lane's k-half with the other
        const float x2v = p + __shfl_xor(p, 32);

        #pragma unroll
        for (int reg = 0; reg < 16; ++reg) {
            const int rl = (reg & 3) + 8 * (reg >> 2) + 4 * half;
            const float x2r = __shfl(x2v, rl);   // lane rl holds x2[rowbase+rl]
            float d = fmaxf(x2r + mu2 - 2.0f * acc[reg], 0.0f);
            s += rv[reg] * d;
        }
    }

    // ---- reduce: wave shuffle -> block -> one atomic ----
    #pragma unroll
    for (int off = 32; off > 0; off >>= 1) s += __shfl_down(s, off);
    if (lane == 0) wsum[wave] = s;
    __syncthreads();
    if (tid == 0) {
        const float t = wsum[0] + wsum[1] + wsum[2] + wsum[3];
        atomicAdd(out, t * (1.0f / 131072.0f));
    }
}

extern "C" void kernel_launch(void* const* d_in, const int* in_sizes, int n_in,
                              void* d_out, int out_size, void* d_ws, size_t ws_size,
                              hipStream_t stream) {
    const float* X   = (const float*)d_in[0];   // [131072, 128]
    const float* r   = (const float*)d_in[1];   // [131072, 128]
    const float* mus = (const float*)d_in[2];   // [128, 128]
    float* out = (float*)d_out;                 // scalar

    zero_out_kernel<<<1, 1, 0, stream>>>(out);  // d_out is poisoned 0xAA each call
    // grid 1024 = exactly 4 blocks/CU resident at __launch_bounds__(256,4); 4 iters each
    isoloss_kernel<<<1024, 256, 0, stream>>>(X, r, mus, out);
}

// Round 3
// 150.955 us; speedup vs baseline: 1.1381x; 1.1381x over previous
//
#include <hip/hip_runtime.h>
#include <hip/hip_bf16.h>

// IsometricLoss: loss = (1/N) * sum_{i,m} r[i,m] * max(||X_i||^2 + ||mu_m||^2 - 2 X_i.mu_m, 0)
// N=131072, M=128, D=128, fp32 in, fp32 scalar out.
//
// R3: single-shot 128-row blocks (grid=1024, no loop), ONE barrier per block.
// Coalesced X staging (16 dwordx4/thread, flat layout) -> bf16 LDS tile; exact
// fp32 x2 via width-32 butterfly during staging; wave owns 32 mus (B in regs),
// iterates 4 row m-tiles from LDS. 64 atomic buckets + tiny final reduce.

typedef __attribute__((ext_vector_type(8)))  short  short8;   // 8 bf16 (MFMA A/B frag)
typedef __attribute__((ext_vector_type(16))) float  float16v; // MFMA 32x32 accumulator

#define LDSP 136  // padded LDS row stride in bf16 elems (128 + 8): 16B aligned, small conflicts

#if defined(__has_builtin)
#if __has_builtin(__builtin_amdgcn_cvt_pk_bf16_f32)
#define HAVE_PK_BF16 1
#endif
#endif

__device__ __forceinline__ unsigned int pk_bf16(float x, float y) {
#ifdef HAVE_PK_BF16
    typedef __attribute__((ext_vector_type(2))) __bf16 bf16x2;
    bf16x2 p = __builtin_amdgcn_cvt_pk_bf16_f32(x, y);
    return __builtin_bit_cast(unsigned int, p);
#else
    unsigned int ux = __float_as_uint(x);
    unsigned int uy = __float_as_uint(y);
    ux += 0x7fffu + ((ux >> 16) & 1u);
    uy += 0x7fffu + ((uy >> 16) & 1u);
    return (ux >> 16) | (uy & 0xffff0000u);
#endif
}

__global__ void zero_ws_kernel(float* ws) { ws[threadIdx.x] = 0.0f; }  // 64 buckets

__global__ void final_reduce_kernel(const float* ws, float* out) {
    const int lane = threadIdx.x;  // 64 threads
    float t = ws[lane];
    #pragma unroll
    for (int off = 32; off > 0; off >>= 1) t += __shfl_down(t, off);
    if (lane == 0) out[0] = t * (1.0f / 131072.0f);
}

__global__ __launch_bounds__(256, 3)
void isoloss_kernel(const float* __restrict__ X,
                    const float* __restrict__ r,
                    const float* __restrict__ mus,
                    float* __restrict__ ws)
{
    const int tid  = threadIdx.x;
    const int blk  = blockIdx.x;        // row-group: rows [blk*128, blk*128+128)
    const int wave = tid >> 6;          // 0..3 -> which 32-mu tile this wave owns
    const int lane = tid & 63;
    const int col  = lane & 31;
    const int half = lane >> 5;

    __shared__ unsigned short ldsA[128 * LDSP]; // X tile bf16, ~34 KB
    __shared__ float x2s[128];
    __shared__ float wsum[4];

    // ---- stage X[128x128] fp32 -> bf16 LDS (fully coalesced), exact fp32 x2 ----
    // flat float4 index f = it*256 + tid; row = it*8 + (tid>>5); col4 = (tid&31)*4
    const float* xbase = X + (size_t)blk * 128 * 128;
    float4 xv[16];
    #pragma unroll
    for (int it = 0; it < 16; ++it)
        xv[it] = *(const float4*)(xbase + (size_t)(it * 256 + tid) * 4);

    #pragma unroll
    for (int it = 0; it < 16; ++it) {
        const float4 v = xv[it];
        float p = v.x*v.x + v.y*v.y + v.z*v.z + v.w*v.w;
        // reduce over the 32-lane group covering this row (xor<32 stays in group)
        p += __shfl_xor(p, 16);
        p += __shfl_xor(p, 8);
        p += __shfl_xor(p, 4);
        p += __shfl_xor(p, 2);
        p += __shfl_xor(p, 1);
        const int row = it * 8 + (tid >> 5);
        if ((tid & 31) == 0) x2s[row] = p;
        uint2 h;
        h.x = pk_bf16(v.x, v.y);
        h.y = pk_bf16(v.z, v.w);
        *(uint2*)&ldsA[row * LDSP + (tid & 31) * 4] = h;
    }

    // ---- preload B fragments (this wave's 32 mus) + exact fp32 mu2 ----
    // (after staging so xv[] regs are dead before bfrag[] goes live)
    short8 bfrag[8];
    float mu2p = 0.0f;
    {
        const float* mrow = mus + (size_t)(wave * 32 + col) * 128 + half * 8;
        #pragma unroll
        for (int ks = 0; ks < 8; ++ks) {
            const float4 a = *(const float4*)(mrow + ks * 16);
            const float4 b = *(const float4*)(mrow + ks * 16 + 4);
            mu2p += a.x*a.x + a.y*a.y + a.z*a.z + a.w*a.w
                  + b.x*b.x + b.y*b.y + b.z*b.z + b.w*b.w;
            union { short8 s8; uint4 u4; } u;
            u.u4.x = pk_bf16(a.x, a.y);
            u.u4.y = pk_bf16(a.z, a.w);
            u.u4.z = pk_bf16(b.x, b.y);
            u.u4.w = pk_bf16(b.z, b.w);
            bfrag[ks] = u.s8;
        }
    }
    const float mu2 = mu2p + __shfl_xor(mu2p, 32);

    __syncthreads();  // the only barrier

    // ---- 4 m-tiles of 32 rows: MFMA cross + fused r-weighted epilogue ----
    float s = 0.0f;
    #pragma unroll
    for (int mt = 0; mt < 4; ++mt) {
        // r loads first: independent of LDS, fly during ds_read+MFMA
        const float* rp = r + (size_t)(blk * 128 + mt * 32) * 128 + wave * 32 + col;
        float rv[16];
        #pragma unroll
        for (int reg = 0; reg < 16; ++reg) {
            const int rl = (reg & 3) + 8 * (reg >> 2) + 4 * half;
            rv[reg] = rp[(size_t)rl * 128];
        }

        float16v acc = {};
        #pragma unroll
        for (int ks = 0; ks < 8; ++ks) {
            const short8 af = *(const short8*)&ldsA[(mt * 32 + col) * LDSP + ks * 16 + half * 8];
            acc = __builtin_amdgcn_mfma_f32_32x32x16_bf16(af, bfrag[ks], acc, 0, 0, 0);
        }

        // x2 broadcast reads: rows mt*32 + q*8 + half*4 .. +3 (16B aligned)
        float4 xq[4];
        #pragma unroll
        for (int q = 0; q < 4; ++q)
            xq[q] = *(const float4*)&x2s[mt * 32 + q * 8 + half * 4];

        #pragma unroll
        for (int reg = 0; reg < 16; ++reg) {
            const float d = fmaxf(xq[reg >> 2][reg & 3] + mu2 - 2.0f * acc[reg], 0.0f);
            s += rv[reg] * d;
        }
    }

    // ---- reduce: wave shuffle -> block -> bucketed atomic ----
    #pragma unroll
    for (int off = 32; off > 0; off >>= 1) s += __shfl_down(s, off);
    if (lane == 0) wsum[wave] = s;
    __syncthreads();
    if (tid == 0)
        atomicAdd(&ws[blk & 63], wsum[0] + wsum[1] + wsum[2] + wsum[3]);
}

extern "C" void kernel_launch(void* const* d_in, const int* in_sizes, int n_in,
                              void* d_out, int out_size, void* d_ws, size_t ws_size,
                              hipStream_t stream) {
    const float* X   = (const float*)d_in[0];   // [131072, 128]
    const float* r   = (const float*)d_in[1];   // [131072, 128]
    const float* mus = (const float*)d_in[2];   // [128, 128]
    float* out = (float*)d_out;                 // scalar
    float* ws  = (float*)d_ws;                  // 64 partial buckets

    zero_ws_kernel<<<1, 64, 0, stream>>>(ws);
    isoloss_kernel<<<1024, 256, 0, stream>>>(X, r, mus, ws);
    final_reduce_kernel<<<1, 64, 0, stream>>>(ws, out);
}